// Round 5
// baseline (303.180 us; speedup 1.0000x reference)
//
#include <hip/hip_runtime.h>
#include <math.h>

// Output: adj (M x M float32), M = N + 4 (N=8192 -> M=8196).
//   adj[i][i] = 1.0  for i < N
//   adj[i][j] = 0.25 for i,j >= N   (bottom-right 4x4 block, incl. diagonal)
//   else 0.
//
// The 262.4 MB output write is irreducible (d_out re-poisoned to 0xAA each
// iteration; exploiting |poison|<threshold is the rigor.md absmax trap — no).
// Floor = ~42 us @ 6.3 TB/s.
//
// Structure: one block per row. Hot loop = UNCONDITIONAL zero 16B stores
// (pure fill stream), one barrier, then thread 0 overwrites the row's single
// special chunk. Native ext_vector_type for __builtin_nontemporal_store
// (HIP's float4 is a class -> rejected by the builtin; round-4 lesson).

typedef float floatx4 __attribute__((ext_vector_type(4)));

__global__ __launch_bounds__(256) void adj_fill_kernel(floatx4* __restrict__ out,
                                                       int N, int M4) {
    const int row = blockIdx.x;
    const size_t base = (size_t)row * (size_t)M4;
    const floatx4 z = (floatx4){0.f, 0.f, 0.f, 0.f};

    // Pure store stream — no compares, no branches in the hot loop.
    for (int c = threadIdx.x; c < M4; c += blockDim.x) {
        __builtin_nontemporal_store(z, &out[base + c]);
    }

    __syncthreads();  // order the special-chunk overwrite after the zero pass

    if (threadIdx.x == 0) {
        if (row < N) {
            const int lane = row & 3;
            floatx4 v;
            v.x = (lane == 0) ? 1.0f : 0.0f;
            v.y = (lane == 1) ? 1.0f : 0.0f;
            v.z = (lane == 2) ? 1.0f : 0.0f;
            v.w = (lane == 3) ? 1.0f : 0.0f;
            out[base + (row >> 2)] = v;
        } else {
            out[base + (M4 - 1)] = (floatx4){0.25f, 0.25f, 0.25f, 0.25f};
        }
    }
}

extern "C" void kernel_launch(void* const* d_in, const int* in_sizes, int n_in,
                              void* d_out, int out_size, void* d_ws, size_t ws_size,
                              hipStream_t stream) {
    (void)d_in; (void)in_sizes; (void)n_in; (void)d_ws; (void)ws_size;

    int M = (int)(sqrt((double)out_size) + 0.5);  // 8196
    int N = M - 4;
    int M4 = M >> 2;                              // 2049 float4 chunks per row

    adj_fill_kernel<<<M, 256, 0, stream>>>((floatx4*)d_out, N, M4);
}

// Round 6
// 285.424 us; speedup vs baseline: 1.0622x; 1.0622x over previous
//
#include <hip/hip_runtime.h>
#include <math.h>

// Output: adj (M x M float32), M = N + 4 (N=8192 -> M=8196).
//   adj[i][i] = 1.0  for i < N
//   adj[i][j] = 0.25 for i,j >= N   (bottom-right 4x4 block, incl. diagonal)
//   else 0.
//
// Best measured structure (R1 = 286 us vs fused variants 295/303 us):
// hipMemsetAsync zero-fill (rocclr fillBufferAligned, ~6.3 TB/s — none of
// our hand-rolled fill loops matched it across R3/R5) + tiny fixup kernel
// for the ~8.2K nonzeros.
//
// The 262.4 MB output write is irreducible: d_out is re-poisoned to 0xAA
// before every timed launch. (Exploiting |0xAA-as-f32| = 3e-13 < 2e-2
// absmax threshold to skip the zero-fill is the rigor.md trap — declined.)
// Controllable floor ~= 42 us fill + ~4 us fixup; the remaining ~236 us of
// dur_us is the harness's own poison/restore fills (1.05 GB ws + out + in).

__global__ void adj_fixup_kernel(float* __restrict__ out, int N, int M) {
    int i = blockIdx.x * blockDim.x + threadIdx.x;
    if (i < N) {
        // diagonal entry, degree-1 node: d_i * 1 * d_i = 1.0
        out[(size_t)i * (size_t)M + (size_t)i] = 1.0f;
    } else if (i < M) {
        // bottom 4 rows: columns N..M-1 all 0.25 (d=0.5 both sides, A=1).
        // Cols N..N+3 are 16B-aligned (N=8192): one dwordx4 store.
        float4 q = make_float4(0.25f, 0.25f, 0.25f, 0.25f);
        *reinterpret_cast<float4*>(&out[(size_t)i * (size_t)M + (size_t)N]) = q;
    }
}

extern "C" void kernel_launch(void* const* d_in, const int* in_sizes, int n_in,
                              void* d_out, int out_size, void* d_ws, size_t ws_size,
                              hipStream_t stream) {
    (void)d_in; (void)in_sizes; (void)n_in; (void)d_ws; (void)ws_size;

    int M = (int)(sqrt((double)out_size) + 0.5);  // 8196
    int N = M - 4;

    // Zero-fill via the runtime's tuned fill kernel (graph-capturable).
    hipMemsetAsync(d_out, 0, (size_t)out_size * sizeof(float), stream);

    // One thread per row writes the row's nonzeros.
    int block = 256;
    int grid = (M + block - 1) / block;
    adj_fixup_kernel<<<grid, block, 0, stream>>>((float*)d_out, N, M);
}